// Round 3
// baseline (621.569 us; speedup 1.0000x reference)
//
#include <hip/hip_runtime.h>

// VQ-VAE quantize, BIT-EXACT replication of the numpy float32 reference:
//   sumx = np.sum(xf*xf, axis=1)   [numpy pairwise_sum, n=64, 8-accumulator order]
//   sume = np.sum(emb*emb, axis=1) [same]
//   M    = (2.0*xf) @ emb.T        [OpenBLAS sgemm: sequential k-order FMA, beta=0]
//   d    = fl32(fl32(sumx + sume) - M);  idx = argmin (first minimum)
// The argmin is decided on the fp32 ulp grid at magnitude ||x||^2 ~ 64 (ulp 7.6e-6),
// so every rounding above must be replicated exactly.

#define N_ROWS   131072
#define Q_ELEMS  8388608
#define NUM_EMB  1024
#define EMB_DIM  64

// numpy pairwise_sum (n=64, contiguous) of fl32(a[i]*a[i]).
// Order: r[j]=sq(a[j]); for i=8..56 step 8: r[j]+=sq(a[i+j]);
//        ((r0+r1)+(r2+r3))+((r4+r5)+(r6+r7))
__device__ __forceinline__ float np_pairwise_sq64(const float* a) {
    #pragma clang fp contract(off)
    float r0 = a[0]*a[0], r1 = a[1]*a[1], r2 = a[2]*a[2], r3 = a[3]*a[3];
    float r4 = a[4]*a[4], r5 = a[5]*a[5], r6 = a[6]*a[6], r7 = a[7]*a[7];
    #pragma unroll
    for (int i = 8; i < 64; i += 8) {
        r0 += a[i+0]*a[i+0];
        r1 += a[i+1]*a[i+1];
        r2 += a[i+2]*a[i+2];
        r3 += a[i+3]*a[i+3];
        r4 += a[i+4]*a[i+4];
        r5 += a[i+5]*a[i+5];
        r6 += a[i+6]*a[i+6];
        r7 += a[i+7]*a[i+7];
    }
    return ((r0 + r1) + (r2 + r3)) + ((r4 + r5) + (r6 + r7));
}

__global__ __launch_bounds__(256) void vq_prep(const float* __restrict__ emb,
                                               float* __restrict__ sume) {
    int k = blockIdx.x * 256 + threadIdx.x;
    if (k < NUM_EMB) {
        sume[k] = np_pairwise_sq64(emb + (k << 6));
    }
}

__global__ __launch_bounds__(256) void vq_main(const float* __restrict__ x,
                                               const float* __restrict__ emb,
                                               const float* __restrict__ sume,
                                               float* __restrict__ out_q,
                                               float* __restrict__ out_idx) {
    const int t   = threadIdx.x;
    const int row = blockIdx.x * 256 + t;

    // Load this thread's 64-float row into registers.
    float rx[EMB_DIM];
    const float4* xr = reinterpret_cast<const float4*>(x + (size_t)row * EMB_DIM);
    #pragma unroll
    for (int j = 0; j < 16; ++j) {
        float4 v = xr[j];
        rx[4*j+0] = v.x; rx[4*j+1] = v.y; rx[4*j+2] = v.z; rx[4*j+3] = v.w;
    }

    // numpy-order fl32 sum of squares, then scale row by 2 (exact, matches 2.0*xf).
    const float sumx = np_pairwise_sq64(rx);
    #pragma unroll
    for (int i = 0; i < EMB_DIM; ++i) rx[i] *= 2.0f;

    float m = 3.4e38f;
    int   b = 0;

    // k-loop: replicate sgemm's sequential-k FMA accumulation exactly.
    // Two independent k-chains for ILP (each chain's internal order untouched).
    for (int k = 0; k < NUM_EMB; k += 2) {
        const float* __restrict__ e0 = emb + (k << 6);        // wave-uniform -> s_load
        float c0 = 0.0f, c1 = 0.0f;
        #pragma unroll
        for (int i = 0; i < EMB_DIM; ++i) {
            c0 = fmaf(rx[i], e0[i],       c0);
            c1 = fmaf(rx[i], e0[64 + i],  c1);
        }
        {
            #pragma clang fp contract(off)
            float t0 = sumx + sume[k];        // fl32 add at magnitude ~64
            float d0 = t0 - c0;               // fl32 sub -> the decisive grid rounding
            float t1 = sumx + sume[k + 1];
            float d1 = t1 - c1;
            if (d0 < m) { m = d0; b = k; }    // strict <  => first-minimum (np.argmin)
            if (d1 < m) { m = d1; b = k + 1; }
        }
    }

    out_idx[row] = (float)b;

    // Cooperative coalesced gather: quantized[row] = emb[idx[row]]
    __shared__ int sidx[256];
    sidx[t] = b;
    __syncthreads();
    const float4* emb4 = reinterpret_cast<const float4*>(emb);
    float4* q4 = reinterpret_cast<float4*>(out_q + (size_t)blockIdx.x * 256 * EMB_DIM);
    #pragma unroll
    for (int i = 0; i < 16; ++i) {
        int e4 = t + i * 256;      // float4 index within this block's 16384-float chunk
        int r  = e4 >> 4;          // row-in-block
        int c  = e4 & 15;          // float4-col
        q4[e4] = emb4[sidx[r] * 16 + c];
    }
}

extern "C" void kernel_launch(void* const* d_in, const int* in_sizes, int n_in,
                              void* d_out, int out_size, void* d_ws, size_t ws_size,
                              hipStream_t stream) {
    const float* x   = (const float*)d_in[0];
    const float* emb = (const float*)d_in[1];
    float* out_q   = (float*)d_out;
    float* out_idx = out_q + Q_ELEMS;
    float* sume    = (float*)d_ws;   // 4 KB

    vq_prep<<<dim3(NUM_EMB / 256), dim3(256), 0, stream>>>(emb, sume);
    vq_main<<<dim3(N_ROWS / 256), dim3(256), 0, stream>>>(x, emb, sume, out_q, out_idx);
}